// Round 8
// baseline (563.670 us; speedup 1.0000x reference)
//
#include <hip/hip_runtime.h>

// Scaled-dot-product attention, bs=4, h=16, S=2048, D=64, f32 in/out.
// Outputs O [64,2048,64] and P=attn_weights [64,2048,2048] (f32, 1.07 GB write).
// R8 structure:
//   1) cvt/transpose pre-passes (bf16 Q*scale, K, V^T)      ~35 us
//   2) lsum_k: j-PARALLEL denominators (16384 waves, 4 partial planes, no atomics)
//   3) attn2_k: single store-heavy loop; l precomputed; stores flow the whole
//      kernel (store duty ~100% vs R7's ~60% phase alternation).
// R3: regular stores only (L2 write-combine keeps HBM at the 1.08 GB minimum).
// R5/R6: reg prefetch null twice -> dropped; slim VGPR buys residency instead.
// R7->R8 LDS: stride-36 f32 rows: bank=(4*row+4*chunk+i)%32 uniform for both
//   column-writes and row-reads -> conflict-free b128, 16B-aligned, no XOR.

#define S_LEN 2048
#define DH 64
#define NHEADS 64  // bs*h

typedef short short8 __attribute__((ext_vector_type(8)));   // 8 x bf16
typedef float f32x4 __attribute__((ext_vector_type(4)));
typedef float f32x16 __attribute__((ext_vector_type(16)));
typedef unsigned short u16;

__device__ __forceinline__ u16 f2bf(float f) {
  union { float f; unsigned u; } x;
  x.f = f;
  unsigned r = x.u + 0x7fffu + ((x.u >> 16) & 1u);  // RNE
  return (u16)(r >> 16);
}

__device__ __forceinline__ unsigned pkbf(float a, float b) {
  return (unsigned)f2bf(a) | ((unsigned)f2bf(b) << 16);  // a -> low, b -> high
}

// v_permlane32_swap_b32: new a[32+i]=old b[i]; new b[i]=old a[32+i]
__device__ __forceinline__ void plswap(unsigned& a, unsigned& b) {
  asm("v_permlane32_swap_b32 %0, %1" : "+v"(a), "+v"(b));
}

// ---- pre-pass: Q * scale -> bf16, same layout ----
__global__ __launch_bounds__(256) void cvt_scale_k(const float* __restrict__ in,
                                                   u16* __restrict__ out,
                                                   float scale, int n4) {
  int i = blockIdx.x * 256 + threadIdx.x;
  if (i >= n4) return;
  float4 v = ((const float4*)in)[i];
  union { u16 s[4]; unsigned long long ll; } o;
  o.s[0] = f2bf(v.x * scale); o.s[1] = f2bf(v.y * scale);
  o.s[2] = f2bf(v.z * scale); o.s[3] = f2bf(v.w * scale);
  ((unsigned long long*)out)[i] = o.ll;
}

// ---- pre-pass: per-head transpose [R][C] f32 -> [C][R] bf16 ----
__global__ __launch_bounds__(256) void transpose_cvt_k(const float* __restrict__ in,
                                                       u16* __restrict__ out,
                                                       int R, int C) {
  __shared__ float tile[64][65];
  const int tilesC = C >> 6;
  const int tilesPerHead = (R >> 6) * tilesC;
  int hb = blockIdx.x;
  int head = hb / tilesPerHead;
  int t = hb - head * tilesPerHead;
  int tr = t / tilesC, tc = t - tr * tilesC;
  const float* ip = in + (size_t)head * R * C + (size_t)tr * 64 * C + (size_t)tc * 64;
  u16* op = out + (size_t)head * R * C + (size_t)tc * 64 * R + (size_t)tr * 64;
  int c = threadIdx.x & 63, r0 = threadIdx.x >> 6;
#pragma unroll
  for (int k = 0; k < 16; ++k) {
    int r = (k << 2) + r0;
    tile[r][c] = ip[(size_t)r * C + c];
  }
  __syncthreads();
#pragma unroll
  for (int k = 0; k < 16; ++k) {
    int orow = (k << 2) + r0;
    op[(size_t)orow * R + c] = f2bf(tile[c][orow]);
  }
}

// ---- denominators, j-parallel: lpart[jc][head][row] = sum_{j in chunk} exp(s) ----
// 4096 blocks x 4 waves; block=(head,qtile of 32 rows); wave wv = j-chunk of 512.
// mfma_f32_32x32x16_bf16: A row=lane&31 k=(lane>>5)*8+i; B col=lane&31 same k;
//                         D col=lane&31, row=(r&3)+8*(r>>2)+4*(lane>>5)
__global__ __launch_bounds__(256) void lsum_k(const u16* __restrict__ Qb,
                                              const u16* __restrict__ Kn,
                                              float* __restrict__ lpart) {
  int bid = blockIdx.x;
  int work = ((bid & 7) << 9) | (bid >> 3);   // bijective: 4096 = 8*512
  int head = work >> 6;
  int qt = work & 63;
  int lane = threadIdx.x & 63;
  int wv = threadIdx.x >> 6;                  // j-chunk 0..3
  int q = lane & 31, hi = lane >> 5;
  int q0 = qt << 5;

  const u16* qp = Qb + (size_t)(head * S_LEN + q0 + q) * DH + hi * 8;
  short8 qf0 = *(const short8*)(qp);
  short8 qf1 = *(const short8*)(qp + 16);
  short8 qf2 = *(const short8*)(qp + 32);
  short8 qf3 = *(const short8*)(qp + 48);
  const u16* kp = Kn + (size_t)head * S_LEN * DH + (size_t)q * DH + hi * 8;

  float ls0 = 0.f, ls1 = 0.f, ls2 = 0.f, ls3 = 0.f;
  int jbeg = wv << 9;
  for (int j0 = jbeg; j0 < jbeg + 512; j0 += 32) {
    const u16* kb = kp + (size_t)j0 * DH;
    short8 k0 = *(const short8*)(kb);
    short8 k1 = *(const short8*)(kb + 16);
    short8 k2 = *(const short8*)(kb + 32);
    short8 k3 = *(const short8*)(kb + 48);
    f32x16 s = {};
    s = __builtin_amdgcn_mfma_f32_32x32x16_bf16(k0, qf0, s, 0, 0, 0);
    s = __builtin_amdgcn_mfma_f32_32x32x16_bf16(k1, qf1, s, 0, 0, 0);
    s = __builtin_amdgcn_mfma_f32_32x32x16_bf16(k2, qf2, s, 0, 0, 0);
    s = __builtin_amdgcn_mfma_f32_32x32x16_bf16(k3, qf3, s, 0, 0, 0);
#pragma unroll
    for (int r = 0; r < 16; r += 4) {
      ls0 += __expf(s[r]);
      ls1 += __expf(s[r + 1]);
      ls2 += __expf(s[r + 2]);
      ls3 += __expf(s[r + 3]);
    }
  }
  float ls = (ls0 + ls1) + (ls2 + ls3);
  ls += __shfl_xor(ls, 32);  // combine hi/lo (disjoint k-halves of each j)
  if (lane < 32)
    lpart[(size_t)(wv * NHEADS + head) * S_LEN + q0 + q] = ls;
}

// ---- attention body: P (coalesced full-line) + O, l precomputed ----
// 2048 blocks x 2 waves (128 thr); wave owns 32 q-rows; stores every iter.
__global__ __launch_bounds__(128, 4) void attn2_k(const u16* __restrict__ Qb,
                                                  const u16* __restrict__ Kn,
                                                  const u16* __restrict__ Vt,
                                                  const float* __restrict__ lpart,
                                                  float* __restrict__ Og,
                                                  float* __restrict__ Pg) {
  __shared__ float tile[2][36 * 32];          // stride-36 rows: conflict-free
  int bid = blockIdx.x;
  int work = ((bid & 7) << 8) | (bid >> 3);   // bijective: 2048 = 8*256
  int head = work >> 5;
  int rblk = work & 31;
  int lane = threadIdx.x & 63;
  int wv = threadIdx.x >> 6;                  // 0..1
  int q = lane & 31;
  int hi = lane >> 5;
  int q0 = (rblk << 6) + (wv << 5);
  float* tw = tile[wv];
  int rq = lane >> 3;   // 0..7 row-in-group for coalesced store reads
  int rc = lane & 7;    // 0..7 16B chunk within the 128B line

  // denominator: sum the 4 partial planes
  size_t lrow = (size_t)head * S_LEN + q0 + q;
  float lsum = lpart[lrow] + lpart[lrow + (size_t)NHEADS * S_LEN] +
               lpart[lrow + 2 * (size_t)NHEADS * S_LEN] +
               lpart[lrow + 3 * (size_t)NHEADS * S_LEN];
  float rl = 1.f / lsum;

  const u16* qp = Qb + (size_t)(head * S_LEN + q0 + q) * DH + hi * 8;
  short8 qf0 = *(const short8*)(qp);
  short8 qf1 = *(const short8*)(qp + 16);
  short8 qf2 = *(const short8*)(qp + 32);
  short8 qf3 = *(const short8*)(qp + 48);

  const u16* kp = Kn + (size_t)head * S_LEN * DH + (size_t)q * DH + hi * 8;
  const u16* vp = Vt + (size_t)head * DH * S_LEN + (size_t)q * S_LEN + hi * 8;

  f32x16 oa = {}, ob = {};
  float* pbW = Pg + (size_t)(head * S_LEN + q0) * S_LEN;

  for (int j0 = 0; j0 < S_LEN; j0 += 32) {
    const u16* kb = kp + (size_t)j0 * DH;
    short8 k0 = *(const short8*)(kb);
    short8 k1 = *(const short8*)(kb + 16);
    short8 k2 = *(const short8*)(kb + 32);
    short8 k3 = *(const short8*)(kb + 48);
    const u16* vj = vp + j0;
    short8 v0 = *(const short8*)(vj);
    short8 v1 = *(const short8*)(vj + 16);
    short8 v2 = *(const short8*)(vj + 32 * S_LEN);
    short8 v3 = *(const short8*)(vj + 32 * S_LEN + 16);

    f32x16 s = {};
    s = __builtin_amdgcn_mfma_f32_32x32x16_bf16(k0, qf0, s, 0, 0, 0);
    s = __builtin_amdgcn_mfma_f32_32x32x16_bf16(k1, qf1, s, 0, 0, 0);
    s = __builtin_amdgcn_mfma_f32_32x32x16_bf16(k2, qf2, s, 0, 0, 0);
    s = __builtin_amdgcn_mfma_f32_32x32x16_bf16(k3, qf3, s, 0, 0, 0);

    float p[16];
#pragma unroll
    for (int r = 0; r < 16; ++r) p[r] = __expf(s[r]) * rl;

    // LDS transpose write: lane q holds j-chunk c=2g+hi (4 contig j) in regs 4g..4g+3
#pragma unroll
    for (int g = 0; g < 4; ++g) {
      f32x4 w = {p[4 * g], p[4 * g + 1], p[4 * g + 2], p[4 * g + 3]};
      *(f32x4*)&tw[q * 36 + (2 * g + hi) * 4] = w;
    }

    // T12 redistribute from regs (independent of LDS): D-layout -> A-frag
    unsigned A0 = pkbf(p[0], p[1]),   A1 = pkbf(p[2], p[3]);
    unsigned B0 = pkbf(p[4], p[5]),   B1 = pkbf(p[6], p[7]);
    plswap(A0, B0);
    plswap(A1, B1);
    unsigned C0 = pkbf(p[8], p[9]),   C1 = pkbf(p[10], p[11]);
    unsigned D0 = pkbf(p[12], p[13]), D1 = pkbf(p[14], p[15]);
    plswap(C0, D0);
    plswap(C1, D1);
    union { unsigned w[4]; short8 v; } pa0u = {{A0, A1, B0, B1}};
    union { unsigned w[4]; short8 v; } pa1u = {{C0, C1, D0, D1}};

    // LDS read back + FULL-LINE P stores: 8 lanes x 16B = one 128B line/row
    float* ps = pbW + j0;
#pragma unroll
    for (int g = 0; g < 4; ++g) {
      int qi = 8 * g + rq;
      f32x4 v = *(const f32x4*)&tw[qi * 36 + rc * 4];
      *(f32x4*)(ps + (size_t)qi * S_LEN + rc * 4) = v;
    }

    oa = __builtin_amdgcn_mfma_f32_32x32x16_bf16(pa0u.v, v0, oa, 0, 0, 0);
    oa = __builtin_amdgcn_mfma_f32_32x32x16_bf16(pa1u.v, v1, oa, 0, 0, 0);
    ob = __builtin_amdgcn_mfma_f32_32x32x16_bf16(pa0u.v, v2, ob, 0, 0, 0);
    ob = __builtin_amdgcn_mfma_f32_32x32x16_bf16(pa1u.v, v3, ob, 0, 0, 0);
  }

  // ---- O epilogue: stride-36 LDS transpose -> full-line stores ----
  float* ogb = Og + (size_t)(head * S_LEN + q0) * DH;
#pragma unroll
  for (int r = 0; r < 16; ++r) {
    int qi = (r & 3) + 8 * (r >> 2) + 4 * hi;
    tw[qi * 36 + q] = oa[r];
  }
#pragma unroll
  for (int g = 0; g < 4; ++g) {
    int qi = 8 * g + rq;
    f32x4 v = *(const f32x4*)&tw[qi * 36 + rc * 4];
    *(f32x4*)(ogb + (size_t)qi * DH + rc * 4) = v;       // d 0..31
  }
#pragma unroll
  for (int r = 0; r < 16; ++r) {
    int qi = (r & 3) + 8 * (r >> 2) + 4 * hi;
    tw[qi * 36 + q] = ob[r];
  }
#pragma unroll
  for (int g = 0; g < 4; ++g) {
    int qi = 8 * g + rq;
    f32x4 v = *(const f32x4*)&tw[qi * 36 + rc * 4];
    *(f32x4*)(ogb + (size_t)qi * DH + 32 + rc * 4) = v;  // d 32..63
  }
}

extern "C" void kernel_launch(void* const* d_in, const int* in_sizes, int n_in,
                              void* d_out, int out_size, void* d_ws, size_t ws_size,
                              hipStream_t stream) {
  const float* q = (const float*)d_in[0];
  const float* k = (const float*)d_in[1];  // [b,h,d,s]
  const float* v = (const float*)d_in[2];  // [b,h,s,d]
  float* Og = (float*)d_out;
  float* Pg = Og + (size_t)NHEADS * S_LEN * DH;

  const size_t elems = (size_t)NHEADS * S_LEN * DH;  // 8,388,608
  u16* Qb = (u16*)d_ws;             // bf16 [h][s][d], pre-scaled
  u16* Kn = Qb + elems;             // bf16 [h][s][d]
  u16* Vt = Kn + elems;             // bf16 [h][d][s]
  float* lpart = (float*)(Vt + elems);  // f32 [4][h][s] partial denominators

  int n4 = (int)(elems / 4);
  cvt_scale_k<<<n4 / 256, 256, 0, stream>>>(q, Qb, 0.125f, n4);
  transpose_cvt_k<<<NHEADS * (S_LEN / 64), 256, 0, stream>>>(k, Kn, DH, S_LEN);
  transpose_cvt_k<<<NHEADS * (S_LEN / 64), 256, 0, stream>>>(v, Vt, S_LEN, DH);
  lsum_k<<<4096, 256, 0, stream>>>(Qb, Kn, lpart);
  attn2_k<<<2048, 128, 0, stream>>>(Qb, Kn, Vt, lpart, Og, Pg);
}

// Round 9
// 562.379 us; speedup vs baseline: 1.0023x; 1.0023x over previous
//
#include <hip/hip_runtime.h>

// Scaled-dot-product attention, bs=4, h=16, S=2048, D=64, f32 in/out.
// Outputs O [64,2048,64] and P=attn_weights [64,2048,2048] (f32, 1.07 GB write).
// R9 model stack (all counter-backed):
//   - bytes are minimal (R1/R4): L2 merges partial lines; WRITE_SIZE = 1.08 GB min
//   - R7: full-line stores fixed L2-ingress transaction rate (+13%)
//   - R9: DRAM row-buffer locality -- 128B per 8KB-strided row = 1 line/page
//     activation. Fix: LDS-batch JSPAN=128 columns -> 512B contiguous per row
//     per burst (4 lines/activation).
// Structure: cvt/transpose prepasses -> lsum_k (j-parallel denominators) ->
// attn2_k (store-heavy single loop, l precomputed).

#define S_LEN 2048
#define DH 64
#define NHEADS 64  // bs*h

typedef short short8 __attribute__((ext_vector_type(8)));   // 8 x bf16
typedef float f32x4 __attribute__((ext_vector_type(4)));
typedef float f32x16 __attribute__((ext_vector_type(16)));
typedef unsigned short u16;

__device__ __forceinline__ u16 f2bf(float f) {
  union { float f; unsigned u; } x;
  x.f = f;
  unsigned r = x.u + 0x7fffu + ((x.u >> 16) & 1u);  // RNE
  return (u16)(r >> 16);
}

__device__ __forceinline__ unsigned pkbf(float a, float b) {
  return (unsigned)f2bf(a) | ((unsigned)f2bf(b) << 16);  // a -> low, b -> high
}

// v_permlane32_swap_b32: new a[32+i]=old b[i]; new b[i]=old a[32+i]
__device__ __forceinline__ void plswap(unsigned& a, unsigned& b) {
  asm("v_permlane32_swap_b32 %0, %1" : "+v"(a), "+v"(b));
}

// ---- pre-pass: Q * scale -> bf16, same layout ----
__global__ __launch_bounds__(256) void cvt_scale_k(const float* __restrict__ in,
                                                   u16* __restrict__ out,
                                                   float scale, int n4) {
  int i = blockIdx.x * 256 + threadIdx.x;
  if (i >= n4) return;
  float4 v = ((const float4*)in)[i];
  union { u16 s[4]; unsigned long long ll; } o;
  o.s[0] = f2bf(v.x * scale); o.s[1] = f2bf(v.y * scale);
  o.s[2] = f2bf(v.z * scale); o.s[3] = f2bf(v.w * scale);
  ((unsigned long long*)out)[i] = o.ll;
}

// ---- pre-pass: per-head transpose [R][C] f32 -> [C][R] bf16 ----
__global__ __launch_bounds__(256) void transpose_cvt_k(const float* __restrict__ in,
                                                       u16* __restrict__ out,
                                                       int R, int C) {
  __shared__ float tile[64][65];
  const int tilesC = C >> 6;
  const int tilesPerHead = (R >> 6) * tilesC;
  int hb = blockIdx.x;
  int head = hb / tilesPerHead;
  int t = hb - head * tilesPerHead;
  int tr = t / tilesC, tc = t - tr * tilesC;
  const float* ip = in + (size_t)head * R * C + (size_t)tr * 64 * C + (size_t)tc * 64;
  u16* op = out + (size_t)head * R * C + (size_t)tc * 64 * R + (size_t)tr * 64;
  int c = threadIdx.x & 63, r0 = threadIdx.x >> 6;
#pragma unroll
  for (int k = 0; k < 16; ++k) {
    int r = (k << 2) + r0;
    tile[r][c] = ip[(size_t)r * C + c];
  }
  __syncthreads();
#pragma unroll
  for (int k = 0; k < 16; ++k) {
    int orow = (k << 2) + r0;
    op[(size_t)orow * R + c] = f2bf(tile[c][orow]);
  }
}

// ---- denominators, j-parallel: lpart[jc][head][row] = sum_{j in chunk} exp(s) ----
// 4096 blocks x 4 waves; block=(head,qtile of 32 rows); wave wv = j-chunk of 512.
__global__ __launch_bounds__(256) void lsum_k(const u16* __restrict__ Qb,
                                              const u16* __restrict__ Kn,
                                              float* __restrict__ lpart) {
  int bid = blockIdx.x;
  int work = ((bid & 7) << 9) | (bid >> 3);   // bijective: 4096 = 8*512
  int head = work >> 6;
  int qt = work & 63;
  int lane = threadIdx.x & 63;
  int wv = threadIdx.x >> 6;                  // j-chunk 0..3
  int q = lane & 31, hi = lane >> 5;
  int q0 = qt << 5;

  const u16* qp = Qb + (size_t)(head * S_LEN + q0 + q) * DH + hi * 8;
  short8 qf0 = *(const short8*)(qp);
  short8 qf1 = *(const short8*)(qp + 16);
  short8 qf2 = *(const short8*)(qp + 32);
  short8 qf3 = *(const short8*)(qp + 48);
  const u16* kp = Kn + (size_t)head * S_LEN * DH + (size_t)q * DH + hi * 8;

  float ls0 = 0.f, ls1 = 0.f, ls2 = 0.f, ls3 = 0.f;
  int jbeg = wv << 9;
  for (int j0 = jbeg; j0 < jbeg + 512; j0 += 32) {
    const u16* kb = kp + (size_t)j0 * DH;
    short8 k0 = *(const short8*)(kb);
    short8 k1 = *(const short8*)(kb + 16);
    short8 k2 = *(const short8*)(kb + 32);
    short8 k3 = *(const short8*)(kb + 48);
    f32x16 s = {};
    s = __builtin_amdgcn_mfma_f32_32x32x16_bf16(k0, qf0, s, 0, 0, 0);
    s = __builtin_amdgcn_mfma_f32_32x32x16_bf16(k1, qf1, s, 0, 0, 0);
    s = __builtin_amdgcn_mfma_f32_32x32x16_bf16(k2, qf2, s, 0, 0, 0);
    s = __builtin_amdgcn_mfma_f32_32x32x16_bf16(k3, qf3, s, 0, 0, 0);
#pragma unroll
    for (int r = 0; r < 16; r += 4) {
      ls0 += __expf(s[r]);
      ls1 += __expf(s[r + 1]);
      ls2 += __expf(s[r + 2]);
      ls3 += __expf(s[r + 3]);
    }
  }
  float ls = (ls0 + ls1) + (ls2 + ls3);
  ls += __shfl_xor(ls, 32);  // combine hi/lo (disjoint k-halves of each j)
  if (lane < 32)
    lpart[(size_t)(wv * NHEADS + head) * S_LEN + q0 + q] = ls;
}

// ---- attention body: JSPAN-batched P stores (512B/row bursts) + O ----
// 2048 blocks x 2 waves; wave owns 32 q-rows. Per JSPAN=128 columns:
// 4 j-tiles of compute accumulate the transposed P panel in LDS [32][132],
// then one burst stores 32 rows x 512 B contiguous (DRAM-page friendly).
__global__ __launch_bounds__(128, 2) void attn2_k(const u16* __restrict__ Qb,
                                                  const u16* __restrict__ Kn,
                                                  const u16* __restrict__ Vt,
                                                  const float* __restrict__ lpart,
                                                  float* __restrict__ Og,
                                                  float* __restrict__ Pg) {
  __shared__ float tile[2][32 * 132];         // per-wave 32 x 128 panel (+4 pad)
  int bid = blockIdx.x;
  int work = ((bid & 7) << 8) | (bid >> 3);   // bijective: 2048 = 8*256
  int head = work >> 5;
  int rblk = work & 31;
  int lane = threadIdx.x & 63;
  int wv = threadIdx.x >> 6;                  // 0..1
  int q = lane & 31;
  int hi = lane >> 5;
  int q0 = (rblk << 6) + (wv << 5);
  float* tw = tile[wv];
  int sl = lane >> 5;   // 0/1: row parity for burst stores
  int jl = lane & 31;   // 16B chunk within the 512B row span
  int rq = lane >> 3;   // epilogue helpers
  int rc = lane & 7;

  size_t lrow = (size_t)head * S_LEN + q0 + q;
  float lsum = lpart[lrow] + lpart[lrow + (size_t)NHEADS * S_LEN] +
               lpart[lrow + 2 * (size_t)NHEADS * S_LEN] +
               lpart[lrow + 3 * (size_t)NHEADS * S_LEN];
  float rl = 1.f / lsum;

  const u16* qp = Qb + (size_t)(head * S_LEN + q0 + q) * DH + hi * 8;
  short8 qf0 = *(const short8*)(qp);
  short8 qf1 = *(const short8*)(qp + 16);
  short8 qf2 = *(const short8*)(qp + 32);
  short8 qf3 = *(const short8*)(qp + 48);

  const u16* kp = Kn + (size_t)head * S_LEN * DH + (size_t)q * DH + hi * 8;
  const u16* vp = Vt + (size_t)head * DH * S_LEN + (size_t)q * S_LEN + hi * 8;

  f32x16 oa = {}, ob = {};
  float* pbW = Pg + (size_t)(head * S_LEN + q0) * S_LEN;

  // K/V prefetch 1 tile ahead (occupancy is 2 waves/SIMD; VGPR headroom is 256)
  short8 kc0 = *(const short8*)(kp);
  short8 kc1 = *(const short8*)(kp + 16);
  short8 kc2 = *(const short8*)(kp + 32);
  short8 kc3 = *(const short8*)(kp + 48);
  short8 vc0 = *(const short8*)(vp);
  short8 vc1 = *(const short8*)(vp + 16);
  short8 vc2 = *(const short8*)(vp + 32 * S_LEN);
  short8 vc3 = *(const short8*)(vp + 32 * S_LEN + 16);

  for (int jb = 0; jb < S_LEN; jb += 128) {
#pragma unroll
    for (int jt = 0; jt < 4; ++jt) {
      int j0 = jb + (jt << 5);
      int jn = (j0 + 32) & (S_LEN - 1);
      const u16* kb = kp + (size_t)jn * DH;
      short8 kn0 = *(const short8*)(kb);
      short8 kn1 = *(const short8*)(kb + 16);
      short8 kn2 = *(const short8*)(kb + 32);
      short8 kn3 = *(const short8*)(kb + 48);
      const u16* vj = vp + jn;
      short8 vn0 = *(const short8*)(vj);
      short8 vn1 = *(const short8*)(vj + 16);
      short8 vn2 = *(const short8*)(vj + 32 * S_LEN);
      short8 vn3 = *(const short8*)(vj + 32 * S_LEN + 16);

      f32x16 s = {};
      s = __builtin_amdgcn_mfma_f32_32x32x16_bf16(kc0, qf0, s, 0, 0, 0);
      s = __builtin_amdgcn_mfma_f32_32x32x16_bf16(kc1, qf1, s, 0, 0, 0);
      s = __builtin_amdgcn_mfma_f32_32x32x16_bf16(kc2, qf2, s, 0, 0, 0);
      s = __builtin_amdgcn_mfma_f32_32x32x16_bf16(kc3, qf3, s, 0, 0, 0);

      float p[16];
#pragma unroll
      for (int r = 0; r < 16; ++r) p[r] = __expf(s[r]) * rl;

      // transposed panel write: lane q, column chunk jt*32 + 8g+4hi (4 contig j)
#pragma unroll
      for (int g = 0; g < 4; ++g) {
        f32x4 w = {p[4 * g], p[4 * g + 1], p[4 * g + 2], p[4 * g + 3]};
        *(f32x4*)&tw[q * 132 + (jt << 5) + 8 * g + 4 * hi] = w;
      }

      // T12 redistribute from regs: D-layout -> A-frag (k = hi*8+i contiguous j)
      unsigned A0 = pkbf(p[0], p[1]),   A1 = pkbf(p[2], p[3]);
      unsigned B0 = pkbf(p[4], p[5]),   B1 = pkbf(p[6], p[7]);
      plswap(A0, B0);
      plswap(A1, B1);
      unsigned C0 = pkbf(p[8], p[9]),   C1 = pkbf(p[10], p[11]);
      unsigned D0 = pkbf(p[12], p[13]), D1 = pkbf(p[14], p[15]);
      plswap(C0, D0);
      plswap(C1, D1);
      union { unsigned w[4]; short8 v; } pa0u = {{A0, A1, B0, B1}};
      union { unsigned w[4]; short8 v; } pa1u = {{C0, C1, D0, D1}};

      oa = __builtin_amdgcn_mfma_f32_32x32x16_bf16(pa0u.v, vc0, oa, 0, 0, 0);
      oa = __builtin_amdgcn_mfma_f32_32x32x16_bf16(pa1u.v, vc1, oa, 0, 0, 0);
      ob = __builtin_amdgcn_mfma_f32_32x32x16_bf16(pa0u.v, vc2, ob, 0, 0, 0);
      ob = __builtin_amdgcn_mfma_f32_32x32x16_bf16(pa1u.v, vc3, ob, 0, 0, 0);

      kc0 = kn0; kc1 = kn1; kc2 = kn2; kc3 = kn3;
      vc0 = vn0; vc1 = vn1; vc2 = vn2; vc3 = vn3;
    }

    // burst: 32 rows x 512 B contiguous each (DRAM-page friendly)
    float* ps = pbW + jb;
#pragma unroll
    for (int rr = 0; rr < 16; ++rr) {
      int row = 2 * rr + sl;
      f32x4 v = *(const f32x4*)&tw[row * 132 + jl * 4];
      *(f32x4*)(ps + (size_t)row * S_LEN + jl * 4) = v;
    }
  }

  // ---- O epilogue: LDS transpose (stride 132) -> full-line stores ----
  float* ogb = Og + (size_t)(head * S_LEN + q0) * DH;
#pragma unroll
  for (int r = 0; r < 16; ++r) {
    int qi = (r & 3) + 8 * (r >> 2) + 4 * hi;
    tw[qi * 132 + q] = oa[r];
  }
#pragma unroll
  for (int g = 0; g < 4; ++g) {
    int qi = 8 * g + rq;
    f32x4 v = *(const f32x4*)&tw[qi * 132 + rc * 4];
    *(f32x4*)(ogb + (size_t)qi * DH + rc * 4) = v;       // d 0..31
  }
#pragma unroll
  for (int r = 0; r < 16; ++r) {
    int qi = (r & 3) + 8 * (r >> 2) + 4 * hi;
    tw[qi * 132 + q] = ob[r];
  }
#pragma unroll
  for (int g = 0; g < 4; ++g) {
    int qi = 8 * g + rq;
    f32x4 v = *(const f32x4*)&tw[qi * 132 + rc * 4];
    *(f32x4*)(ogb + (size_t)qi * DH + 32 + rc * 4) = v;  // d 32..63
  }
}

extern "C" void kernel_launch(void* const* d_in, const int* in_sizes, int n_in,
                              void* d_out, int out_size, void* d_ws, size_t ws_size,
                              hipStream_t stream) {
  const float* q = (const float*)d_in[0];
  const float* k = (const float*)d_in[1];  // [b,h,d,s]
  const float* v = (const float*)d_in[2];  // [b,h,s,d]
  float* Og = (float*)d_out;
  float* Pg = Og + (size_t)NHEADS * S_LEN * DH;

  const size_t elems = (size_t)NHEADS * S_LEN * DH;  // 8,388,608
  u16* Qb = (u16*)d_ws;             // bf16 [h][s][d], pre-scaled
  u16* Kn = Qb + elems;             // bf16 [h][s][d]
  u16* Vt = Kn + elems;             // bf16 [h][d][s]
  float* lpart = (float*)(Vt + elems);  // f32 [4][h][s] partial denominators

  int n4 = (int)(elems / 4);
  cvt_scale_k<<<n4 / 256, 256, 0, stream>>>(q, Qb, 0.125f, n4);
  transpose_cvt_k<<<NHEADS * (S_LEN / 64), 256, 0, stream>>>(k, Kn, DH, S_LEN);
  transpose_cvt_k<<<NHEADS * (S_LEN / 64), 256, 0, stream>>>(v, Vt, S_LEN, DH);
  lsum_k<<<4096, 256, 0, stream>>>(Qb, Kn, lpart);
  attn2_k<<<2048, 128, 0, stream>>>(Qb, Kn, Vt, lpart, Og, Pg);
}

// Round 10
// 405.695 us; speedup vs baseline: 1.3894x; 1.3862x over previous
//
#include <hip/hip_runtime.h>

// Scaled-dot-product attention, bs=4, h=16, S=2048, D=64, f32 in/out.
// Outputs O [64,2048,64] and P=attn_weights [64,2048,2048] (f32, 1.07 GB write).
// Base = R7 (best, 537 us): fused 2-pass, swapped-QK^T 32x32, LDS-transposed
// FULL-LINE P/O stores. R10 single change: P stores are nontemporal.
//   R3 tested nt x PARTIAL lines -> 1.67x amplification (confound).
//   R10 tests nt x FULL 128B lines -> stream to HBM, bypass L2 write-allocate,
//   freeing L2 for the K/V read path. WRITE_SIZE must stay ~1.081e6 KB.

#define S_LEN 2048
#define DH 64
#define NHEADS 64  // bs*h

typedef short short8 __attribute__((ext_vector_type(8)));   // 8 x bf16
typedef float f32x4 __attribute__((ext_vector_type(4)));
typedef float f32x16 __attribute__((ext_vector_type(16)));
typedef unsigned short u16;

__device__ __forceinline__ u16 f2bf(float f) {
  union { float f; unsigned u; } x;
  x.f = f;
  unsigned r = x.u + 0x7fffu + ((x.u >> 16) & 1u);  // RNE
  return (u16)(r >> 16);
}

__device__ __forceinline__ unsigned pkbf(float a, float b) {
  return (unsigned)f2bf(a) | ((unsigned)f2bf(b) << 16);  // a -> low, b -> high
}

// v_permlane32_swap_b32: new a[32+i]=old b[i]; new b[i]=old a[32+i]
__device__ __forceinline__ void plswap(unsigned& a, unsigned& b) {
  asm("v_permlane32_swap_b32 %0, %1" : "+v"(a), "+v"(b));
}

// ---- pre-pass: Q * scale -> bf16, same layout ----
__global__ __launch_bounds__(256) void cvt_scale_k(const float* __restrict__ in,
                                                   u16* __restrict__ out,
                                                   float scale, int n4) {
  int i = blockIdx.x * 256 + threadIdx.x;
  if (i >= n4) return;
  float4 v = ((const float4*)in)[i];
  union { u16 s[4]; unsigned long long ll; } o;
  o.s[0] = f2bf(v.x * scale); o.s[1] = f2bf(v.y * scale);
  o.s[2] = f2bf(v.z * scale); o.s[3] = f2bf(v.w * scale);
  ((unsigned long long*)out)[i] = o.ll;
}

// ---- pre-pass: per-head transpose [R][C] f32 -> [C][R] bf16 ----
__global__ __launch_bounds__(256) void transpose_cvt_k(const float* __restrict__ in,
                                                       u16* __restrict__ out,
                                                       int R, int C) {
  __shared__ float tile[64][65];
  const int tilesC = C >> 6;
  const int tilesPerHead = (R >> 6) * tilesC;
  int hb = blockIdx.x;
  int head = hb / tilesPerHead;
  int t = hb - head * tilesPerHead;
  int tr = t / tilesC, tc = t - tr * tilesC;
  const float* ip = in + (size_t)head * R * C + (size_t)tr * 64 * C + (size_t)tc * 64;
  u16* op = out + (size_t)head * R * C + (size_t)tc * 64 * R + (size_t)tr * 64;
  int c = threadIdx.x & 63, r0 = threadIdx.x >> 6;
#pragma unroll
  for (int k = 0; k < 16; ++k) {
    int r = (k << 2) + r0;
    tile[r][c] = ip[(size_t)r * C + c];
  }
  __syncthreads();
#pragma unroll
  for (int k = 0; k < 16; ++k) {
    int orow = (k << 2) + r0;
    op[(size_t)orow * R + c] = f2bf(tile[c][orow]);
  }
}

// ---- fused attention, swapped 32x32, LDS-transposed full-line stores ----
// Layouts (bf16): Qb [h][s][d] (pre-scaled), Kn [h][s][d], Vt [h][d][s].
// Block = 128 q-rows = 4 waves x 32. Per wave, j-tiles of 32.
// mfma_f32_32x32x16_bf16:  A row=lane&31, k=(lane>>5)*8+i (8 contig)
//                          B col=lane&31, k=(lane>>5)*8+i
//                          D col=lane&31, row=(r&3)+8*(r>>2)+4*(lane>>5)
__global__ __launch_bounds__(256, 3) void attn_k(const u16* __restrict__ Qb,
                                                 const u16* __restrict__ Kn,
                                                 const u16* __restrict__ Vt,
                                                 float* __restrict__ Og,
                                                 float* __restrict__ Pg) {
  // per-wave 32x32 f32 transpose tile; row stride 32 floats (128 B).
  __shared__ float tile[4][32 * 32];
  int bid = blockIdx.x;
  // bijective XCD swizzle: 1024 blocks, XCD x gets heads 8x..8x+7 (K+V = 4MB = L2)
  int work = ((bid & 7) << 7) | (bid >> 3);
  int head = work >> 4;
  int rblk = work & 15;
  int lane = threadIdx.x & 63;
  int wv = threadIdx.x >> 6;
  int q = lane & 31;
  int hi = lane >> 5;
  int q0 = (rblk << 7) + (wv << 5);
  float* tw = tile[wv];
  int rq = lane >> 3;   // 0..7: row-within-group for coalesced store reads
  int rc = lane & 7;    // 0..7: 16B chunk index within the 128B line

  // Q B-fragments, resident
  const u16* qp = Qb + (size_t)(head * S_LEN + q0 + q) * DH + hi * 8;
  short8 qf0 = *(const short8*)(qp);
  short8 qf1 = *(const short8*)(qp + 16);
  short8 qf2 = *(const short8*)(qp + 32);
  short8 qf3 = *(const short8*)(qp + 48);

  const u16* kp = Kn + (size_t)head * S_LEN * DH + (size_t)q * DH + hi * 8;
  const u16* vp = Vt + (size_t)head * DH * S_LEN + (size_t)q * S_LEN + hi * 8;

  // ---- pass 1: l[q] = sum_j exp(s); K double-buffered ----
  float ls0 = 0.f, ls1 = 0.f, ls2 = 0.f, ls3 = 0.f;
  short8 kc0 = *(const short8*)(kp);
  short8 kc1 = *(const short8*)(kp + 16);
  short8 kc2 = *(const short8*)(kp + 32);
  short8 kc3 = *(const short8*)(kp + 48);
  for (int j0 = 0; j0 < S_LEN; j0 += 32) {
    int jn = (j0 + 32) & (S_LEN - 1);          // wrap: last prefetch reloads j=0
    const u16* kb = kp + (size_t)jn * DH;
    short8 kn0 = *(const short8*)(kb);
    short8 kn1 = *(const short8*)(kb + 16);
    short8 kn2 = *(const short8*)(kb + 32);
    short8 kn3 = *(const short8*)(kb + 48);
    f32x16 s = {};
    s = __builtin_amdgcn_mfma_f32_32x32x16_bf16(kc0, qf0, s, 0, 0, 0);
    s = __builtin_amdgcn_mfma_f32_32x32x16_bf16(kc1, qf1, s, 0, 0, 0);
    s = __builtin_amdgcn_mfma_f32_32x32x16_bf16(kc2, qf2, s, 0, 0, 0);
    s = __builtin_amdgcn_mfma_f32_32x32x16_bf16(kc3, qf3, s, 0, 0, 0);
#pragma unroll
    for (int r = 0; r < 16; r += 4) {
      ls0 += __expf(s[r]);
      ls1 += __expf(s[r + 1]);
      ls2 += __expf(s[r + 2]);
      ls3 += __expf(s[r + 3]);
    }
    kc0 = kn0; kc1 = kn1; kc2 = kn2; kc3 = kn3;
  }
  float ls = (ls0 + ls1) + (ls2 + ls3);
  ls += __shfl_xor(ls, 32);  // combine hi/lo halves (disjoint j subsets)
  float rl = 1.f / ls;

  // ---- pass 2: coalesced nt P write + O = P*V ----
  // kc* already holds the j=0 K tile (wrapped prefetch from pass 1).
  f32x16 oa = {}, ob = {};
  float* pbW = Pg + (size_t)(head * S_LEN + q0) * S_LEN;

  short8 vc0 = *(const short8*)(vp);
  short8 vc1 = *(const short8*)(vp + 16);
  short8 vc2 = *(const short8*)(vp + 32 * S_LEN);
  short8 vc3 = *(const short8*)(vp + 32 * S_LEN + 16);

  for (int j0 = 0; j0 < S_LEN; j0 += 32) {
    int jn = (j0 + 32) & (S_LEN - 1);
    const u16* kb = kp + (size_t)jn * DH;
    short8 kn0 = *(const short8*)(kb);
    short8 kn1 = *(const short8*)(kb + 16);
    short8 kn2 = *(const short8*)(kb + 32);
    short8 kn3 = *(const short8*)(kb + 48);
    const u16* vj = vp + jn;
    short8 vn0 = *(const short8*)(vj);
    short8 vn1 = *(const short8*)(vj + 16);
    short8 vn2 = *(const short8*)(vj + 32 * S_LEN);
    short8 vn3 = *(const short8*)(vj + 32 * S_LEN + 16);

    f32x16 s = {};
    s = __builtin_amdgcn_mfma_f32_32x32x16_bf16(kc0, qf0, s, 0, 0, 0);
    s = __builtin_amdgcn_mfma_f32_32x32x16_bf16(kc1, qf1, s, 0, 0, 0);
    s = __builtin_amdgcn_mfma_f32_32x32x16_bf16(kc2, qf2, s, 0, 0, 0);
    s = __builtin_amdgcn_mfma_f32_32x32x16_bf16(kc3, qf3, s, 0, 0, 0);

    float p[16];
#pragma unroll
    for (int r = 0; r < 16; ++r) p[r] = __expf(s[r]) * rl;

    // LDS transpose write: lane holds column q, regs 4g..4g+3 = j-chunk c=2g+hi.
    // chunk-XOR swizzle keeps the column-write ~4-way instead of 32-way.
#pragma unroll
    for (int g = 0; g < 4; ++g) {
      int phys = (2 * g + hi) ^ (q & 7);
      f32x4 w = {p[4 * g], p[4 * g + 1], p[4 * g + 2], p[4 * g + 3]};
      *(f32x4*)&tw[q * 32 + phys * 4] = w;
    }

    // T12 redistribute from regs (independent of LDS): D-layout -> A-frag
    unsigned A0 = pkbf(p[0], p[1]),   A1 = pkbf(p[2], p[3]);
    unsigned B0 = pkbf(p[4], p[5]),   B1 = pkbf(p[6], p[7]);
    plswap(A0, B0);
    plswap(A1, B1);
    unsigned C0 = pkbf(p[8], p[9]),   C1 = pkbf(p[10], p[11]);
    unsigned D0 = pkbf(p[12], p[13]), D1 = pkbf(p[14], p[15]);
    plswap(C0, D0);
    plswap(C1, D1);
    union { unsigned w[4]; short8 v; } pa0u = {{A0, A1, B0, B1}};
    union { unsigned w[4]; short8 v; } pa1u = {{C0, C1, D0, D1}};

    oa = __builtin_amdgcn_mfma_f32_32x32x16_bf16(pa0u.v, vc0, oa, 0, 0, 0);
    oa = __builtin_amdgcn_mfma_f32_32x32x16_bf16(pa1u.v, vc1, oa, 0, 0, 0);
    ob = __builtin_amdgcn_mfma_f32_32x32x16_bf16(pa0u.v, vc2, ob, 0, 0, 0);
    ob = __builtin_amdgcn_mfma_f32_32x32x16_bf16(pa1u.v, vc3, ob, 0, 0, 0);

    // LDS read back + FULL-LINE nontemporal P stores:
    // 8 lanes x 16B = one whole 128B line -> streams to HBM, no L2 allocate.
    float* ps = pbW + j0;
#pragma unroll
    for (int g = 0; g < 4; ++g) {
      int qi = 8 * g + rq;
      int phys = rc ^ (qi & 7);
      f32x4 v = *(const f32x4*)&tw[qi * 32 + phys * 4];
      __builtin_nontemporal_store(v, (f32x4*)(ps + (size_t)qi * S_LEN + rc * 4));
    }

    kc0 = kn0; kc1 = kn1; kc2 = kn2; kc3 = kn3;
    vc0 = vn0; vc1 = vn1; vc2 = vn2; vc3 = vn3;
  }

  // ---- O epilogue: LDS transpose -> full-line stores (regular; O is 32 MB) ----
  float* ogb = Og + (size_t)(head * S_LEN + q0) * DH;
#pragma unroll
  for (int r = 0; r < 16; ++r) {
    int qi = (r & 3) + 8 * (r >> 2) + 4 * hi;
    tw[qi * 32 + q] = oa[r];   // bank = q -> conflict-free
  }
#pragma unroll
  for (int g = 0; g < 4; ++g) {
    int qi = 8 * g + rq;
    f32x4 v = *(const f32x4*)&tw[qi * 32 + rc * 4];
    *(f32x4*)(ogb + (size_t)qi * DH + rc * 4) = v;   // d 0..31: full 128B line
  }
#pragma unroll
  for (int r = 0; r < 16; ++r) {
    int qi = (r & 3) + 8 * (r >> 2) + 4 * hi;
    tw[qi * 32 + q] = ob[r];
  }
#pragma unroll
  for (int g = 0; g < 4; ++g) {
    int qi = 8 * g + rq;
    f32x4 v = *(const f32x4*)&tw[qi * 32 + rc * 4];
    *(f32x4*)(ogb + (size_t)qi * DH + 32 + rc * 4) = v;  // d 32..63
  }
}

extern "C" void kernel_launch(void* const* d_in, const int* in_sizes, int n_in,
                              void* d_out, int out_size, void* d_ws, size_t ws_size,
                              hipStream_t stream) {
  const float* q = (const float*)d_in[0];
  const float* k = (const float*)d_in[1];  // [b,h,d,s]
  const float* v = (const float*)d_in[2];  // [b,h,s,d]
  float* Og = (float*)d_out;
  float* Pg = Og + (size_t)NHEADS * S_LEN * DH;

  const size_t elems = (size_t)NHEADS * S_LEN * DH;  // 8,388,608
  u16* Qb = (u16*)d_ws;           // bf16 [h][s][d], pre-scaled
  u16* Kn = Qb + elems;           // bf16 [h][s][d]
  u16* Vt = Kn + elems;           // bf16 [h][d][s]

  int n4 = (int)(elems / 4);
  cvt_scale_k<<<n4 / 256, 256, 0, stream>>>(q, Qb, 0.125f, n4);
  transpose_cvt_k<<<NHEADS * (S_LEN / 64), 256, 0, stream>>>(k, Kn, DH, S_LEN);
  transpose_cvt_k<<<NHEADS * (S_LEN / 64), 256, 0, stream>>>(v, Vt, S_LEN, DH);
  attn_k<<<NHEADS * (S_LEN / 128), 256, 0, stream>>>(Qb, Kn, Vt, Og, Pg);
}